// Round 1
// baseline (439.943 us; speedup 1.0000x reference)
//
#include <hip/hip_runtime.h>
#include <hip/hip_bf16.h>

typedef __hip_bfloat16 bf16;
typedef __attribute__((ext_vector_type(8))) short short8;
typedef __attribute__((ext_vector_type(4))) float floatx4;
typedef __attribute__((ext_vector_type(4))) short shortx4;

static constexpr int BATCH = 4;
static constexpr int CH    = 512;   // C
static constexpr int SEQ   = 4096;  // H*W
static constexpr int DM    = 512;   // model dim

__device__ __forceinline__ void gload16(const void* g, void* l) {
  __builtin_amdgcn_global_load_lds(
      (const __attribute__((address_space(1))) unsigned int*)g,
      (__attribute__((address_space(3))) unsigned int*)l,
      16, 0, 0);
}

// ---------------------------------------------------------------------------
// Weight fp32 -> bf16 conversion (4 matrices of 512x512)
// ---------------------------------------------------------------------------
__global__ __launch_bounds__(256) void cvt_weights(
    const float* __restrict__ w0, const float* __restrict__ w1,
    const float* __restrict__ w2, const float* __restrict__ w3,
    bf16* __restrict__ out) {
  const float* src = (blockIdx.y == 0) ? w0 : (blockIdx.y == 1) ? w1
                   : (blockIdx.y == 2) ? w2 : w3;
  int idx = blockIdx.x * 256 + threadIdx.x;
  out[(long)blockIdx.y * (DM * CH) + idx] = __float2bfloat16(src[idx]);
}

// ---------------------------------------------------------------------------
// x (b,c,s) fp32 -> xT (b,s,c) bf16, 64x64 LDS tiles
// ---------------------------------------------------------------------------
__global__ __launch_bounds__(256) void transpose_cvt(
    const float* __restrict__ x, bf16* __restrict__ xT) {
  __shared__ float tile[64][65];
  const int s0 = blockIdx.x * 64, c0 = blockIdx.y * 64;
  const float* xb = x + (long)blockIdx.z * CH * SEQ;
  bf16* xTb = xT + (long)blockIdx.z * SEQ * CH;
  const int t = threadIdx.x;
  const int sl = t & 63, cq = t >> 6;
  #pragma unroll
  for (int i = 0; i < 16; ++i) {
    int cl = cq * 16 + i;
    tile[cl][sl] = xb[(long)(c0 + cl) * SEQ + s0 + sl];
  }
  __syncthreads();
  const int cl2 = t & 63, sq = t >> 6;
  #pragma unroll
  for (int i = 0; i < 16; ++i) {
    int sl2 = sq * 16 + i;
    xTb[(long)(s0 + sl2) * CH + c0 + cl2] = __float2bfloat16(tile[cl2][sl2]);
  }
}

// ---------------------------------------------------------------------------
// Generic BT GEMM: C[m,n] = sum_k A[m,k]*B[n,k], A: MxK row-major, B: NxK
// row-major, both bf16. 128x128 tile, BK=32, 256 threads (4 waves in 2x2).
// MODE 0: bf16 out = acc + bias[col], C[row*ldc+col]
// MODE 1: bf16 out = acc + bias[col], transposed C[col*ldc+row]
// MODE 2: bf16 out = acc * scale,     C[row*ldc+col]
// MODE 4: f32  out = acc + bias[col], transposed C[col*ldc+row]
// ---------------------------------------------------------------------------
template <int MODE>
__global__ __launch_bounds__(256) void gemm_bt(
    const bf16* __restrict__ A, long sAz,
    const bf16* __restrict__ B, long sBz,
    void* __restrict__ Cv, long sCz,
    const float* __restrict__ bias, float scale,
    int M, int N, int K, int ldc) {
  __shared__ bf16 At[128 * 32];
  __shared__ bf16 Bt[128 * 32];
  const int tid = threadIdx.x;
  const int z = blockIdx.z;
  const long lK = K;
  const bf16* Ab = A + (long)z * sAz + (long)blockIdx.y * 128 * lK;
  const bf16* Bb = B + (long)z * sBz + (long)blockIdx.x * 128 * lK;

  const int w = tid >> 6, lane = tid & 63;
  const int wm = (w & 1) << 6, wn = (w >> 1) << 6;
  const int l16 = lane & 15, quad = lane >> 4;

  floatx4 acc[4][4];
  #pragma unroll
  for (int i = 0; i < 4; ++i)
    #pragma unroll
    for (int j = 0; j < 4; ++j) acc[i][j] = (floatx4)(0.0f);

  const int row0 = tid >> 2;          // 0..63
  const int col0 = (tid & 3) << 3;    // 0,8,16,24 (bf16 elements)
  const int nk = K >> 5;
  for (int kt = 0; kt < nk; ++kt) {
    const bf16* Ak = Ab + (kt << 5);
    const bf16* Bk = Bb + (kt << 5);
    // stage 128x32 A and B tiles, 16B per lane, LDS dest = linear chunk order
    gload16(Ak + (long)row0 * lK + col0,        (char*)At + tid * 16);
    gload16(Ak + (long)(row0 + 64) * lK + col0, (char*)At + (tid + 256) * 16);
    gload16(Bk + (long)row0 * lK + col0,        (char*)Bt + tid * 16);
    gload16(Bk + (long)(row0 + 64) * lK + col0, (char*)Bt + (tid + 256) * 16);
    __syncthreads();
    short8 af[4], bfr[4];
    #pragma unroll
    for (int i = 0; i < 4; ++i)
      af[i] = *(const short8*)(At + (wm + i * 16 + l16) * 32 + (quad << 3));
    #pragma unroll
    for (int j = 0; j < 4; ++j)
      bfr[j] = *(const short8*)(Bt + (wn + j * 16 + l16) * 32 + (quad << 3));
    #pragma unroll
    for (int i = 0; i < 4; ++i)
      #pragma unroll
      for (int j = 0; j < 4; ++j)
        acc[i][j] = __builtin_amdgcn_mfma_f32_16x16x32_bf16(af[i], bfr[j],
                                                            acc[i][j], 0, 0, 0);
    __syncthreads();
  }

  const int mbase = blockIdx.y * 128 + wm + quad * 4;
  const int nbase = blockIdx.x * 128 + wn + l16;
  #pragma unroll
  for (int i = 0; i < 4; ++i) {
    const int row = mbase + i * 16;
    #pragma unroll
    for (int j = 0; j < 4; ++j) {
      const int col = nbase + j * 16;
      floatx4 v = acc[i][j];
      if constexpr (MODE == 0) {
        bf16* C = (bf16*)Cv + (long)z * sCz;
        const float bb = bias[col];
        #pragma unroll
        for (int r = 0; r < 4; ++r)
          C[(long)(row + r) * ldc + col] = __float2bfloat16(v[r] + bb);
      } else if constexpr (MODE == 1) {
        bf16* C = (bf16*)Cv + (long)z * sCz;
        const float bb = bias[col];
        alignas(8) bf16 tmp[4];
        #pragma unroll
        for (int r = 0; r < 4; ++r) tmp[r] = __float2bfloat16(v[r] + bb);
        *(shortx4*)(C + (long)col * ldc + row) = *(const shortx4*)tmp;
      } else if constexpr (MODE == 2) {
        bf16* C = (bf16*)Cv + (long)z * sCz;
        #pragma unroll
        for (int r = 0; r < 4; ++r)
          C[(long)(row + r) * ldc + col] = __float2bfloat16(v[r] * scale);
      } else {  // MODE 4
        float* C = (float*)Cv + (long)z * sCz;
        const float bb = bias[col];
        floatx4 o_;
        #pragma unroll
        for (int r = 0; r < 4; ++r) o_[r] = v[r] + bb;
        *(floatx4*)(C + (long)col * ldc + row) = o_;
      }
    }
  }
}

// ---------------------------------------------------------------------------
// In-place row softmax over bf16 rows of length 4096. One block per row.
// ---------------------------------------------------------------------------
__global__ __launch_bounds__(256) void softmax_rows(bf16* __restrict__ sim) {
  bf16* p = sim + (long)blockIdx.y * ((long)SEQ * SEQ) + (long)blockIdx.x * SEQ;
  uint4* p4 = (uint4*)p;
  const int t = threadIdx.x;
  union U { uint4 u; ushort h[8]; } d[2];
  d[0].u = p4[t];
  d[1].u = p4[t + 256];
  float v[16];
  float mx = -3.0e38f;
  #pragma unroll
  for (int i = 0; i < 16; ++i) {
    v[i] = __uint_as_float(((unsigned)d[i >> 3].h[i & 7]) << 16);
    mx = fmaxf(mx, v[i]);
  }
  #pragma unroll
  for (int o = 32; o > 0; o >>= 1) mx = fmaxf(mx, __shfl_xor(mx, o));
  __shared__ float redmax[4], redsum[4];
  if ((t & 63) == 0) redmax[t >> 6] = mx;
  __syncthreads();
  mx = fmaxf(fmaxf(redmax[0], redmax[1]), fmaxf(redmax[2], redmax[3]));
  float sum = 0.f;
  #pragma unroll
  for (int i = 0; i < 16; ++i) {
    v[i] = __expf(v[i] - mx);
    sum += v[i];
  }
  #pragma unroll
  for (int o = 32; o > 0; o >>= 1) sum += __shfl_xor(sum, o);
  if ((t & 63) == 0) redsum[t >> 6] = sum;
  __syncthreads();
  sum = redsum[0] + redsum[1] + redsum[2] + redsum[3];
  const float inv = 1.0f / sum;
  union Hb { __hip_bfloat16 h; ushort u; };
  #pragma unroll
  for (int i = 0; i < 16; ++i) {
    Hb hb;
    hb.h = __float2bfloat16(v[i] * inv);
    d[i >> 3].h[i & 7] = hb.u;
  }
  p4[t] = d[0].u;
  p4[t + 256] = d[1].u;
}

// ---------------------------------------------------------------------------
extern "C" void kernel_launch(void* const* d_in, const int* in_sizes, int n_in,
                              void* d_out, int out_size, void* d_ws,
                              size_t ws_size, hipStream_t stream) {
  const float* q  = (const float*)d_in[0];
  const float* Wq = (const float*)d_in[1];
  const float* bq = (const float*)d_in[2];
  const float* Wk = (const float*)d_in[3];
  const float* bk = (const float*)d_in[4];
  const float* Wv = (const float*)d_in[5];
  const float* bv = (const float*)d_in[6];
  const float* Wo = (const float*)d_in[7];
  const float* bo = (const float*)d_in[8];
  float* out = (float*)d_out;

  bf16* ws = (bf16*)d_ws;
  const long WSZ = (long)DM * CH;         // 262144 elems per weight matrix
  const long XSZ = (long)SEQ * CH;        // 2097152 elems per batch
  const long SSZ = (long)SEQ * SEQ;       // 16777216 elems per batch
  bf16* Wqb = ws;
  bf16* Wkb = Wqb + WSZ;
  bf16* Wvb = Wqb + 2 * WSZ;
  bf16* Wob = Wqb + 3 * WSZ;
  bf16* xT  = Wqb + 4 * WSZ;
  bf16* Qb  = xT + BATCH * XSZ;
  bf16* Kb  = Qb + BATCH * XSZ;
  bf16* Vt  = Kb + BATCH * XSZ;   // (b, d, s) layout
  bf16* Ob  = Vt + BATCH * XSZ;
  bf16* Sim = Ob + BATCH * XSZ;   // (b, s, t) bf16, softmaxed in place

  cvt_weights<<<dim3(WSZ / 256, 4), 256, 0, stream>>>(Wq, Wk, Wv, Wo, ws);
  transpose_cvt<<<dim3(SEQ / 64, CH / 64, BATCH), 256, 0, stream>>>(q, xT);

  // Q = xT * Wq^T + bq  (4096x512x512), bf16 out
  gemm_bt<0><<<dim3(4, 32, BATCH), 256, 0, stream>>>(
      xT, XSZ, Wqb, 0, Qb, XSZ, bq, 1.f, SEQ, DM, CH, DM);
  gemm_bt<0><<<dim3(4, 32, BATCH), 256, 0, stream>>>(
      xT, XSZ, Wkb, 0, Kb, XSZ, bk, 1.f, SEQ, DM, CH, DM);
  // V stored transposed: Vt[d][s]
  gemm_bt<1><<<dim3(4, 32, BATCH), 256, 0, stream>>>(
      xT, XSZ, Wvb, 0, Vt, XSZ, bv, 1.f, SEQ, DM, CH, SEQ);
  // sim = Q*K^T * scale (4096x4096x512), bf16 out
  gemm_bt<2><<<dim3(32, 32, BATCH), 256, 0, stream>>>(
      Qb, XSZ, Kb, XSZ, Sim, SSZ, nullptr, 0.04419417382415922f,
      SEQ, SEQ, DM, SEQ);
  softmax_rows<<<dim3(SEQ, BATCH), 256, 0, stream>>>(Sim);
  // o = P * V  (A = probs 4096x4096, B = Vt as NxK), bf16 out
  gemm_bt<2><<<dim3(4, 32, BATCH), 256, 0, stream>>>(
      Sim, SSZ, Vt, XSZ, Ob, XSZ, nullptr, 1.0f, SEQ, DM, SEQ, DM);
  // y = o * Wo^T + bo, stored transposed into d_out as (b, c, s) fp32
  gemm_bt<4><<<dim3(4, 32, BATCH), 256, 0, stream>>>(
      Ob, XSZ, Wob, 0, out, XSZ, bo, 1.f, SEQ, CH, DM, SEQ);
}